// Round 11
// baseline (1351.320 us; speedup 1.0000x reference)
//
#include <hip/hip_runtime.h>
#include <hip/hip_bf16.h>

typedef __hip_bfloat16 bf16;
typedef short bf16x8 __attribute__((ext_vector_type(8)));
typedef float f32x4 __attribute__((ext_vector_type(4)));

#define DEV __device__ __forceinline__

DEV float bf2f(bf16 v) { return __bfloat162float(v); }
DEV bf16 f2bf(float v) { return __float2bfloat16(v); }
DEV unsigned short bfr(float f) {
  bf16 h = __float2bfloat16(f);
  return *reinterpret_cast<unsigned short*>(&h);
}
DEV float shf(unsigned short u) {
  unsigned int x = ((unsigned int)u) << 16;
  return *reinterpret_cast<float*>(&x);
}
DEV float gelu_exact(float x) { return 0.5f * x * (1.0f + erff(x * 0.70710678118654752f)); }

DEV float ldw(const void* p, long i, int isb) {
  return isb ? __bfloat162float(((const bf16*)p)[i]) : ((const float*)p)[i];
}

// ---------------- dtype detection + flag constants ----------------
__global__ void k_detect(const unsigned short* __restrict__ u, int* __restrict__ flag) {
  __shared__ int bad;
  if (threadIdx.x == 0) bad = 0;
  __syncthreads();
  for (int i = threadIdx.x; i < 8192; i += 256) {
    int expo = (u[i] >> 7) & 0xFF;
    if (expo >= 138) atomicOr(&bad, 1);
  }
  __syncthreads();
  if (threadIdx.x == 0) *flag = bad ? 0 : 1;
}
__global__ void k_setone(int* p) { *p = 1; }

// ---------------- convert (bf16|fp32) -> fp32 ----------------
__global__ void k_cvt(const void* __restrict__ s, float* __restrict__ d, int n,
                      const int* __restrict__ fl) {
  int isb = *fl;
  int i = blockIdx.x * blockDim.x + threadIdx.x;
  if (i < n) d[i] = ldw(s, i, isb);
}

__global__ void k_zerosh(unsigned short* __restrict__ p, int n8) {
  int i = blockIdx.x * blockDim.x + threadIdx.x;
  if (i < n8) { uint4 z = {0, 0, 0, 0}; *(uint4*)(p + (long)i * 8) = z; }
}

// tokenizer weight [192][49] (at element offset 9408) -> bf16 [192][64] zero-padded
__global__ void k_padtokw(const void* __restrict__ tw, bf16* __restrict__ dst,
                          const int* __restrict__ fl) {
  int isb = *fl;
  int i = blockIdx.x * blockDim.x + threadIdx.x;
  if (i >= 12288) return;
  int n = i >> 6, k = i & 63;
  float v = (k < 49) ? ldw(tw, 9408 + (long)n * 49 + k, isb) : 0.0f;
  dst[i] = f2bf(v);
}

// conv weight pack: dst[s][np][icp] bf16 from src [OC][ICT][9], channel remap feats|warp|flow|0
__global__ void k_packw(const void* __restrict__ src, bf16* __restrict__ dst,
                        int OC, int C, int ICT, int NP, int ICP, int n,
                        const int* __restrict__ fl) {
  int isb = *fl;
  int i = blockIdx.x * blockDim.x + threadIdx.x;
  if (i >= n) return;
  int s = i / (NP * ICP);
  int r = i - s * NP * ICP;
  int oc = r / ICP, icp = r - oc * ICP;
  float v = 0.0f;
  if (oc < OC) {
    int ic = -1;
    if (icp < C) ic = icp;
    else if (icp < 2 * C) ic = icp - C + C + 2;
    else if (icp < 2 * C + 2) ic = icp - 2 * C + C;
    if (ic >= 0 && ic < ICT) v = ldw(src, ((long)oc * ICT + ic) * 9 + s, isb);
  }
  dst[i] = f2bf(v);
}

// feats [F][C][HW] -> pixel-major bf16 [F][HW][C]; one thread per 8-channel group
__global__ void k_trans_feats(const void* __restrict__ in, bf16* __restrict__ Fp,
                              int F, int C, int HW, const int* __restrict__ fl) {
  int isb = *fl;
  int cpg = C >> 3;
  int n = F * HW * cpg;
  int i = blockIdx.x * blockDim.x + threadIdx.x;
  if (i >= n) return;
  int p = i % HW;
  int rem = i / HW;
  int c8 = rem % cpg;
  int f = rem / cpg;
  long base = (long)f * C * HW + (long)(c8 * 8) * HW + p;
  union { unsigned short u[8]; uint4 v; } pk;
#pragma unroll
  for (int j = 0; j < 8; ++j) pk.u[j] = bfr(ldw(in, base + (long)j * HW, isb));
  *(uint4*)((unsigned short*)Fp + ((long)f * HW + p) * C + c8 * 8) = pk.v;
}

// per-(pixel, c8) copy of feats frame b into padded A interior
__global__ void k_fill_feats(const bf16* __restrict__ Fp, bf16* __restrict__ Ap,
                             int C, int ICP, int H, int W) {
  int HW = H * W;
  int cpg = C >> 3;
  int n = 2 * HW * cpg;
  int i = blockIdx.x * blockDim.x + threadIdx.x;
  if (i >= n) return;
  int g = i % cpg;
  int rem = i / cpg;
  int p = rem % HW;
  int b = rem / HW;
  int h = p / W, w = p - h * W;
  const unsigned short* src = (const unsigned short*)Fp + ((long)b * HW + p) * C + g * 8;
  unsigned short* dst = (unsigned short*)Ap +
      ((long)b * (H + 2) * (W + 2) + (long)(h + 1) * (W + 2) + w + 1) * ICP + g * 8;
  *(uint4*)dst = *(const uint4*)src;
}

// per-(pixel, c8): warped frame channels [C,2C); g==0 also writes flow [2C,2C+2)
__global__ void k_warp_pack(const bf16* __restrict__ Fp, const float* __restrict__ flow,
                            bf16* __restrict__ Ap, int C, int ICP, int H, int W) {
  int HW = H * W;
  int cpg = C >> 3;
  int n = 2 * HW * cpg;
  int i = blockIdx.x * blockDim.x + threadIdx.x;
  if (i >= n) return;
  int g = i % cpg;
  int rem = i / cpg;
  int p = rem % HW;
  int b = rem / HW;
  int h = p / W, w = p - h * W;
  const float* fl = flow + (long)b * 2 * HW;
  float fx = fl[p], fy = fl[HW + p];
  unsigned short* drow = (unsigned short*)Ap +
      ((long)b * (H + 2) * (W + 2) + (long)(h + 1) * (W + 2) + w + 1) * ICP;
  if (g == 0) { drow[2 * C] = bfr(fx); drow[2 * C + 1] = bfr(fy); }
  float x = fminf(fmaxf((float)w + fx, 0.0f), (float)(W - 1));
  float y = fminf(fmaxf((float)h + fy, 0.0f), (float)(H - 1));
  int x0 = (int)floorf(x), y0 = (int)floorf(y);
  int x1 = min(x0 + 1, W - 1), y1 = min(y0 + 1, H - 1);
  float wx = x - (float)x0, wy = y - (float)y0;
  float w00 = (1 - wx) * (1 - wy), w01 = wx * (1 - wy);
  float w10 = (1 - wx) * wy, w11 = wx * wy;
  const unsigned short* f = (const unsigned short*)Fp + (long)(b + 1) * HW * C;
  int c = g * 8;
  union { unsigned short u[8]; uint4 v; } a = { .v = *(const uint4*)(f + (long)(y0 * W + x0) * C + c) };
  union { unsigned short u[8]; uint4 v; } bb = { .v = *(const uint4*)(f + (long)(y0 * W + x1) * C + c) };
  union { unsigned short u[8]; uint4 v; } cc = { .v = *(const uint4*)(f + (long)(y1 * W + x0) * C + c) };
  union { unsigned short u[8]; uint4 v; } dd = { .v = *(const uint4*)(f + (long)(y1 * W + x1) * C + c) };
  union { unsigned short u[8]; uint4 v; } o;
#pragma unroll
  for (int j = 0; j < 8; ++j) {
    float v = shf(a.u[j]) * w00 + shf(bb.u[j]) * w01 + shf(cc.u[j]) * w10 + shf(dd.u[j]) * w11;
    o.u[j] = bfr(v);
  }
  *(uint4*)(drow + C + c) = o.v;
}

// ---------------- MFMA implicit-GEMM 3x3 conv, barrier-light schedule -----------------
template <int MW, int NT, int MODE>
__global__ __launch_bounds__(256) void k_conv_mfma(
    const bf16* __restrict__ Ap, int ICP, const bf16* __restrict__ Wp,
    const float* __restrict__ bias, const float* __restrict__ res,
    void* __restrict__ out, int NOUT, int H, int W, int lgW) {
  constexpr int NWN = 4 / MW;
  constexpr int BM = MW * 16;
  constexpr int BN = NWN * NT * 16;
  __shared__ unsigned short Asm[198][40];
  __shared__ unsigned short Wsm[9 * BN][40];
  int tid = threadIdx.x;
  int wv = tid >> 6, ln = tid & 63, quad = ln >> 4, l16 = ln & 15;
  int wm = wv % MW, wn = wv / MW;
  int n0 = blockIdx.x * BN;
  int m0 = blockIdx.y * BM;
  int b = blockIdx.z;
  int Wp2 = W + 2;
  int CW = (BM < W) ? BM : W;
  int lgCW = (CW == 64) ? 6 : 5;
  int RO = (BM > W) ? (BM >> lgW) : 1;
  int ACW = CW + 2;
  int AR = (RO + 2) * ACW;
  int py0 = m0 >> lgW;
  int px0 = m0 & (W - 1);
  const unsigned short* A = (const unsigned short*)Ap + (long)b * (H + 2) * Wp2 * ICP;
  int NPr = (MODE == 0) ? NOUT : 16;
  int nk = ICP >> 5;
  f32x4 acc[NT] = {};
  int mm_local = wm * 16 + l16;
  int plr = mm_local >> lgCW;
  int plc = mm_local & (CW - 1);
  for (int kc = 0; kc < nk; ++kc) {
    for (int i = tid; i < AR * 4; i += 256) {
      int r = i >> 2, c4 = i & 3;
      int sr = r / ACW, sc = r - sr * ACW;
      long g = ((long)(py0 + sr) * Wp2 + px0 + sc) * ICP + kc * 32 + c4 * 8;
      *(uint4*)&Asm[r][c4 * 8] = *(const uint4*)(A + g);
    }
    for (int i = tid; i < 9 * BN * 4; i += 256) {
      int r = i >> 2, c4 = i & 3;
      int s = r / BN, nl = r - s * BN;
      long g = ((long)s * NPr + n0 + nl) * ICP + kc * 32 + c4 * 8;
      *(uint4*)&Wsm[r][c4 * 8] = *(const uint4*)((const unsigned short*)Wp + g);
    }
    __syncthreads();
#pragma unroll
    for (int s = 0; s < 9; ++s) {
      int ky = s / 3, kx = s - ky * 3;
      bf16x8 af = *(const bf16x8*)&Asm[(plr + ky) * ACW + plc + kx][quad * 8];
#pragma unroll
      for (int nt = 0; nt < NT; ++nt) {
        bf16x8 wf = *(const bf16x8*)&Wsm[s * BN + (wn * NT + nt) * 16 + l16][quad * 8];
        acc[nt] = __builtin_amdgcn_mfma_f32_16x16x32_bf16(af, wf, acc[nt], 0, 0, 0);
      }
    }
    __syncthreads();
  }
  if (MODE == 0) {
#pragma unroll
    for (int nt = 0; nt < NT; ++nt) {
      int n = n0 + (wn * NT + nt) * 16 + l16;
      float bv = bias[n];
#pragma unroll
      for (int r = 0; r < 4; ++r) {
        int mmo = m0 + wm * 16 + quad * 4 + r;
        int py = mmo >> lgW, px = mmo & (W - 1);
        float v = gelu_exact(acc[nt][r] + bv);
        ((unsigned short*)out)[((long)b * (H + 2) * Wp2 + (long)(py + 1) * Wp2 + px + 1) * NOUT + n]
            = bfr(v);
      }
    }
  } else {
    int n = l16;
    if (wn == 0 && n < 2) {
      float bv = bias[n];
      int HW = H * W;
#pragma unroll
      for (int r = 0; r < 4; ++r) {
        int mmo = m0 + wm * 16 + quad * 4 + r;
        float v = acc[0][r] + bv + res[(long)b * 2 * HW + (long)n * HW + mmo];
        ((float*)out)[(long)b * 2 * HW + (long)n * HW + mmo] = v;
      }
    }
  }
}

// ---------------- local correlation from pixel-major bf16 Fp2, bf16 out, stride 64 -------
__global__ void k_corr(const bf16* __restrict__ Fp2, bf16* __restrict__ corrT) {
  __shared__ unsigned short f1r[128];
  int p = blockIdx.x;
  int b = blockIdx.y;
  int t = threadIdx.x;  // 64
  const unsigned short* f1 = (const unsigned short*)Fp2 + ((long)b * 1024 + p) * 128;
  if (t < 16) *(uint4*)&f1r[t * 8] = *(const uint4*)(f1 + t * 8);
  __syncthreads();
  long rowo = ((long)b * 1024 + p) * 64;
  if (t < 49) {
    int dy = t / 7 - 3, dx = t % 7 - 3;
    int h = p >> 5, w = p & 31;
    int p2 = (((h - dy) & 31) << 5) | ((w - dx) & 31);
    const unsigned short* f2 = (const unsigned short*)Fp2 + ((long)(b + 1) * 1024 + p2) * 128;
    float s = 0.0f;
    for (int c = 0; c < 128; c += 8) {
      union { unsigned short u[8]; uint4 v; } av = { .v = *(const uint4*)&f1r[c] };
      union { unsigned short u[8]; uint4 v; } bv = { .v = *(const uint4*)(f2 + c) };
#pragma unroll
      for (int j = 0; j < 8; ++j) s += shf(av.u[j]) * shf(bv.u[j]);
    }
    corrT[rowo + t] = f2bf(s * 0.08838834764831845f);
  } else {
    corrT[rowo + t] = f2bf(0.0f);
  }
}

// ---------------- LayerNorm (D=192), 4 rows/block, bf16 out (used once after EMA) --------
__global__ __launch_bounds__(256) void k_ln(const float* __restrict__ src, bf16* __restrict__ dst,
                     const void* __restrict__ w, long woff,
                     const void* __restrict__ b, long boff,
                     const int* __restrict__ fl) {
  int isb = *fl;
  int row = blockIdx.x * 4 + (threadIdx.x >> 6);
  int t = threadIdx.x & 63;
  const float* s = src + (long)row * 192;
  float e0 = s[t], e1 = s[t + 64], e2 = s[t + 128];
  float sum = e0 + e1 + e2;
  for (int o = 32; o; o >>= 1) sum += __shfl_xor(sum, o);
  float mean = sum * (1.0f / 192.0f);
  float d0 = e0 - mean, d1 = e1 - mean, d2 = e2 - mean;
  float vs = d0 * d0 + d1 * d1 + d2 * d2;
  for (int o = 32; o; o >>= 1) vs += __shfl_xor(vs, o);
  float rstd = rsqrtf(vs * (1.0f / 192.0f) + 1e-5f);
  bf16* o_ = dst + (long)row * 192;
  o_[t]       = f2bf(d0 * rstd * ldw(w, woff + t, isb)       + ldw(b, boff + t, isb));
  o_[t + 64]  = f2bf(d1 * rstd * ldw(w, woff + t + 64, isb)  + ldw(b, boff + t + 64, isb));
  o_[t + 128] = f2bf(d2 * rstd * ldw(w, woff + t + 128, isb) + ldw(b, boff + t + 128, isb));
}

// ---------------- MFMA bf16 GEMM (plain) ----------------
// AMODE: 0 = fp32 A, 1 = bf16 A. VT: scatter V-region (n>=384) into vt[b][h][48][1024].
template <int ACT, bool HASRES, int AMODE, int OUTBF, int VT>
__global__ __launch_bounds__(256) void k_gemm_mfma(
    const void* __restrict__ A, const void* __restrict__ W, long woff,
    const void* __restrict__ bias, long boff, const int* __restrict__ flb,
    const float* __restrict__ res, void* __restrict__ C,
    int M, int N, int K, const int* __restrict__ fl,
    bf16* __restrict__ vtout) {
  int isb = *fl;
  __shared__ unsigned short Asm[64][40];
  __shared__ unsigned short Wsm[64][40];
  int tid = threadIdx.x;
  int wv = tid >> 6, ln = tid & 63;
  int quad = ln >> 4, l16 = ln & 15;
  int m0 = blockIdx.y * 64, n0 = blockIdx.x * 64;
  int srow = tid >> 2;
  int skc = (tid & 3) * 8;
  f32x4 acc[4] = {};
  for (int k0 = 0; k0 < K; k0 += 32) {
    if (AMODE == 1) {
      const unsigned short* ap = (const unsigned short*)A + (long)(m0 + srow) * K + k0 + skc;
      *(uint4*)&Asm[srow][skc] = *(const uint4*)ap;
    } else {
      const float* ap = (const float*)A + (long)(m0 + srow) * K + k0 + skc;
      float4 a0 = *(const float4*)ap;
      float4 a1 = *(const float4*)(ap + 4);
      union { unsigned short u[8]; uint4 v; } pk;
      pk.u[0] = bfr(a0.x); pk.u[1] = bfr(a0.y); pk.u[2] = bfr(a0.z); pk.u[3] = bfr(a0.w);
      pk.u[4] = bfr(a1.x); pk.u[5] = bfr(a1.y); pk.u[6] = bfr(a1.z); pk.u[7] = bfr(a1.w);
      *(uint4*)&Asm[srow][skc] = pk.v;
    }
    {
      long eo = woff + (long)(n0 + srow) * K + k0 + skc;
      if (isb) {
        *(uint4*)&Wsm[srow][skc] = *(const uint4*)((const unsigned short*)W + eo);
      } else {
        const float* wp = (const float*)W + eo;
        float4 w0 = *(const float4*)wp;
        float4 w1 = *(const float4*)(wp + 4);
        union { unsigned short u[8]; uint4 v; } pk;
        pk.u[0] = bfr(w0.x); pk.u[1] = bfr(w0.y); pk.u[2] = bfr(w0.z); pk.u[3] = bfr(w0.w);
        pk.u[4] = bfr(w1.x); pk.u[5] = bfr(w1.y); pk.u[6] = bfr(w1.z); pk.u[7] = bfr(w1.w);
        *(uint4*)&Wsm[srow][skc] = pk.v;
      }
    }
    __syncthreads();
    bf16x8 af = *(const bf16x8*)&Asm[wv * 16 + l16][quad * 8];
#pragma unroll
    for (int nt = 0; nt < 4; ++nt) {
      bf16x8 wf = *(const bf16x8*)&Wsm[nt * 16 + l16][quad * 8];
      acc[nt] = __builtin_amdgcn_mfma_f32_16x16x32_bf16(af, wf, acc[nt], 0, 0, 0);
    }
    __syncthreads();
  }
  int isbb = *flb;
#pragma unroll
  for (int nt = 0; nt < 4; ++nt) {
    int n = n0 + nt * 16 + l16;
    float bv = ldw(bias, boff + n, isbb);
#pragma unroll
    for (int r = 0; r < 4; ++r) {
      int m = m0 + wv * 16 + quad * 4 + r;
      float v = acc[nt][r] + bv;
      if (HASRES) v += res[(long)m * N + n];
      if (ACT == 1) v = gelu_exact(v);
      if (OUTBF) ((bf16*)C)[(long)m * N + n] = f2bf(v);
      else ((float*)C)[(long)m * N + n] = v;
      if (VT) {
        if (n >= 384) {
          int hh = (n - 384) / 48, dd = (n - 384) % 48;
          int row = m & 1023, bb = m >> 10;
          vtout[((long)(bb * 4 + hh) * 48 + dd) * 1024 + row] = f2bf(v);
        }
      }
    }
  }
}

// ---------------- MFMA GEMM + fused LayerNorm (N=192, full row per block) ----------------
// BM=64, BN=192; 4 waves each own 16 rows x 192 cols (12 accs). Writes fp32 xout and
// bf16 tbout = LN(xout) with exact per-row mean/var via in-quad shfl reduction.
// AMODE: 1 = bf16 A; 2 = A from 4-way split-K attention partials (fused merge).
template <int ACT, bool HASRES, int AMODE>
__global__ __launch_bounds__(256) void k_gemm_ln(
    const void* __restrict__ A, const void* __restrict__ W, long woff,
    const void* __restrict__ bias, long boff,
    const float* __restrict__ res, float* __restrict__ xout, bf16* __restrict__ tbout,
    const void* __restrict__ lnw, long lnwoff, const void* __restrict__ lnb, long lnboff,
    int M, int K, const int* __restrict__ fl, const int* __restrict__ flb,
    const unsigned short* __restrict__ mop, const float* __restrict__ mml) {
  int isb = *fl;
  __shared__ unsigned short Asm[64][40];
  __shared__ unsigned short Wsm[192][40];
  int tid = threadIdx.x;
  int wv = tid >> 6, ln = tid & 63;
  int quad = ln >> 4, l16 = ln & 15;
  int m0 = blockIdx.x * 64;
  int srow = tid >> 2;
  int skc = (tid & 3) * 8;
  f32x4 acc[12] = {};
  for (int k0 = 0; k0 < K; k0 += 32) {
    if (AMODE == 1) {
      const unsigned short* ap = (const unsigned short*)A + (long)(m0 + srow) * K + k0 + skc;
      *(uint4*)&Asm[srow][skc] = *(const uint4*)ap;
    } else {
      // fused attention merge (4 splits; bf16 O partials, fp32 m/l)
      int m = m0 + srow;
      int row = m & 1023, bb = m >> 10;
      int ks = k0 + skc;
      int h = ks / 48;
      int d0 = ks - h * 48;
      long idx[4];
      float ms[4], ls[4];
      float Ms = -1e30f;
#pragma unroll
      for (int s = 0; s < 4; ++s) {
        idx[s] = (((long)s * 2 + bb) * 4 + h) * 1024 + row;
        ms[s] = mml[idx[s] * 2];
        ls[s] = mml[idx[s] * 2 + 1];
        Ms = fmaxf(Ms, ms[s]);
      }
      float e[4], L = 0.0f;
#pragma unroll
      for (int s = 0; s < 4; ++s) { e[s] = __expf(ms[s] - Ms); L += ls[s] * e[s]; }
      float invL = 1.0f / L;
      union { unsigned short u[8]; uint4 v; } pk;
#pragma unroll
      for (int j = 0; j < 8; ++j) {
        float o = 0.0f;
#pragma unroll
        for (int s = 0; s < 4; ++s) o += shf(mop[idx[s] * 48 + d0 + j]) * e[s];
        pk.u[j] = bfr(o * invL);
      }
      *(uint4*)&Asm[srow][skc] = pk.v;
    }
    for (int i = tid; i < 768; i += 256) {
      int r = i >> 2, c4 = (i & 3) * 8;
      long eo = woff + (long)r * K + k0 + c4;
      if (isb) {
        *(uint4*)&Wsm[r][c4] = *(const uint4*)((const unsigned short*)W + eo);
      } else {
        const float* wp = (const float*)W + eo;
        float4 w0 = *(const float4*)wp;
        float4 w1 = *(const float4*)(wp + 4);
        union { unsigned short u[8]; uint4 v; } pk;
        pk.u[0] = bfr(w0.x); pk.u[1] = bfr(w0.y); pk.u[2] = bfr(w0.z); pk.u[3] = bfr(w0.w);
        pk.u[4] = bfr(w1.x); pk.u[5] = bfr(w1.y); pk.u[6] = bfr(w1.z); pk.u[7] = bfr(w1.w);
        *(uint4*)&Wsm[r][c4] = pk.v;
      }
    }
    __syncthreads();
    bf16x8 af = *(const bf16x8*)&Asm[wv * 16 + l16][quad * 8];
#pragma unroll
    for (int nt = 0; nt < 12; ++nt) {
      bf16x8 wf = *(const bf16x8*)&Wsm[nt * 16 + l16][quad * 8];
      acc[nt] = __builtin_amdgcn_mfma_f32_16x16x32_bf16(af, wf, acc[nt], 0, 0, 0);
    }
    __syncthreads();
  }
  int isbb = *flb;
  float bvv[12];
#pragma unroll
  for (int nt = 0; nt < 12; ++nt) bvv[nt] = ldw(bias, boff + nt * 16 + l16, isbb);
#pragma unroll
  for (int r = 0; r < 4; ++r) {
    int m = m0 + wv * 16 + quad * 4 + r;
    float v12[12];
    float s = 0.0f;
#pragma unroll
    for (int nt = 0; nt < 12; ++nt) {
      float v = acc[nt][r] + bvv[nt];
      if (HASRES) v += res[(long)m * 192 + nt * 16 + l16];
      if (ACT == 1) v = gelu_exact(v);
      v12[nt] = v;
      s += v;
      xout[(long)m * 192 + nt * 16 + l16] = v;
    }
    for (int o = 8; o; o >>= 1) s += __shfl_xor(s, o);
    float mean = s * (1.0f / 192.0f);
    float ss = 0.0f;
#pragma unroll
    for (int nt = 0; nt < 12; ++nt) { float d = v12[nt] - mean; ss += d * d; }
    for (int o = 8; o; o >>= 1) ss += __shfl_xor(ss, o);
    float rstd = rsqrtf(ss * (1.0f / 192.0f) + 1e-5f);
#pragma unroll
    for (int nt = 0; nt < 12; ++nt) {
      int n = nt * 16 + l16;
      tbout[(long)m * 192 + n] =
          f2bf((v12[nt] - mean) * rstd * ldw(lnw, lnwoff + n, isbb) + ldw(lnb, lnboff + n, isbb));
    }
  }
}

// ---------------- fp32 GEMM (head output; FLOW=1 writes [b][2][1024] layout) -------------
template <int ACT, bool HASRES, int FLOW>
__global__ __launch_bounds__(256) void k_gemm(const float* __restrict__ A,
                                              const void* __restrict__ W, long woff,
                                              const void* __restrict__ bias, long boff,
                                              const float* __restrict__ res,
                                              float* __restrict__ C, int M, int N, int K, int Kw,
                                              const int* __restrict__ fl) {
  int isb = *fl;
  __shared__ float As[16][132];
  __shared__ float Ws[16][68];
  int tid = threadIdx.x;
  int tx = tid & 15, ty = tid >> 4;
  int m0 = blockIdx.y * 128, n0 = blockIdx.x * 64;
  float acc[8][4] = {};
  for (int k0 = 0; k0 < K; k0 += 16) {
#pragma unroll
    for (int i = 0; i < 2; ++i) {
      int idx4 = tid + i * 256;
      int mm = idx4 >> 2, kc = (idx4 & 3) * 4;
      float4 v = *(const float4*)(A + (long)(m0 + mm) * K + k0 + kc);
      As[kc][mm] = v.x; As[kc + 1][mm] = v.y; As[kc + 2][mm] = v.z; As[kc + 3][mm] = v.w;
    }
#pragma unroll
    for (int i = 0; i < 4; ++i) {
      int idx = tid + i * 256;
      int nn = idx >> 4, kk = idx & 15;
      int gn = n0 + nn, gk = k0 + kk;
      Ws[kk][nn] = (gn < N && gk < Kw) ? ldw(W, woff + (long)gn * Kw + gk, isb) : 0.0f;
    }
    __syncthreads();
#pragma unroll
    for (int kk = 0; kk < 16; ++kk) {
      float4 a0 = *(const float4*)&As[kk][ty * 8];
      float4 a1 = *(const float4*)&As[kk][ty * 8 + 4];
      float4 w4 = *(const float4*)&Ws[kk][tx * 4];
      float av[8] = {a0.x, a0.y, a0.z, a0.w, a1.x, a1.y, a1.z, a1.w};
      float wv[4] = {w4.x, w4.y, w4.z, w4.w};
#pragma unroll
      for (int i = 0; i < 8; ++i)
#pragma unroll
        for (int j = 0; j < 4; ++j) acc[i][j] += av[i] * wv[j];
    }
    __syncthreads();
  }
#pragma unroll
  for (int i = 0; i < 8; ++i) {
    int gm = m0 + ty * 8 + i;
#pragma unroll
    for (int j = 0; j < 4; ++j) {
      int gn = n0 + tx * 4 + j;
      if (gn >= N) continue;
      float v = acc[i][j] + ldw(bias, boff + gn, isb);
      if (HASRES) v += res[(long)gm * N + gn];
      if (ACT == 1) v = gelu_exact(v);
      if (FLOW) {
        int bb2 = gm >> 10, p = gm & 1023;
        C[((long)bb2 * 2 + gn) * 1024 + p] = v;
      } else {
        C[(long)gm * N + gn] = v;
      }
    }
  }
}

// ---------------- MFMA flash attention, split-K (4 splits of 4 chunks) -------------------
__global__ __launch_bounds__(256) void k_attn_mfma(const bf16* __restrict__ qkv,
                                                   const bf16* __restrict__ vt,
                                                   unsigned short* __restrict__ opart,
                                                   float* __restrict__ ml) {
  __shared__ unsigned short Qs[64][72];
  __shared__ unsigned short Ks[64][72];
  __shared__ unsigned short Vs[48][72];
  __shared__ unsigned short Ps[64][72];
  int tid = threadIdx.x;
  int wv = tid >> 6, ln = tid & 63, quad = ln >> 4, l16 = ln & 15;
  int h = blockIdx.y, b = blockIdx.z;
  int qt = blockIdx.x >> 2, s = blockIdx.x & 3;
  int q0 = qt * 64;
  const unsigned short* qp = (const unsigned short*)qkv + (long)b * 1024 * 576;
  const unsigned short* vp = (const unsigned short*)vt + ((long)(b * 4 + h) * 48) * 1024;
  for (int i = tid; i < 384; i += 256) {
    int r = i / 6, c = i % 6;
    *(uint4*)&Qs[r][c * 8] = *(const uint4*)(qp + (long)(q0 + r) * 576 + h * 48 + c * 8);
  }
  for (int i = tid; i < 128; i += 256) {
    int r = i >> 1, c = 6 + (i & 1);
    uint4 z = {0, 0, 0, 0};
    *(uint4*)&Qs[r][c * 8] = z;
  }
  float m[4] = {-1e30f, -1e30f, -1e30f, -1e30f};
  float l[4] = {0.0f, 0.0f, 0.0f, 0.0f};
  f32x4 accO[3] = {};
  const float SC = 0.14433756729740643f;
  for (int kc = s * 4; kc < s * 4 + 4; ++kc) {
    int k0 = kc * 64;
    for (int i = tid; i < 384; i += 256) {
      int r = i / 6, c = i % 6;
      *(uint4*)&Ks[r][c * 8] = *(const uint4*)(qp + (long)(k0 + r) * 576 + 192 + h * 48 + c * 8);
    }
    for (int i = tid; i < 128; i += 256) {
      int r = i >> 1, c = 6 + (i & 1);
      uint4 z = {0, 0, 0, 0};
      *(uint4*)&Ks[r][c * 8] = z;
    }
    for (int i = tid; i < 384; i += 256) {
      int d = i >> 3, c = i & 7;
      *(uint4*)&Vs[d][c * 8] = *(const uint4*)(vp + (long)d * 1024 + k0 + c * 8);
    }
    __syncthreads();
    f32x4 accS[4] = {};
    bf16x8 a0 = *(const bf16x8*)&Qs[wv * 16 + l16][quad * 8];
    bf16x8 a1 = *(const bf16x8*)&Qs[wv * 16 + l16][32 + quad * 8];
#pragma unroll
    for (int ct = 0; ct < 4; ++ct) {
      bf16x8 b0 = *(const bf16x8*)&Ks[ct * 16 + l16][quad * 8];
      bf16x8 b1 = *(const bf16x8*)&Ks[ct * 16 + l16][32 + quad * 8];
      accS[ct] = __builtin_amdgcn_mfma_f32_16x16x32_bf16(a0, b0, accS[ct], 0, 0, 0);
      accS[ct] = __builtin_amdgcn_mfma_f32_16x16x32_bf16(a1, b1, accS[ct], 0, 0, 0);
    }
#pragma unroll
    for (int r = 0; r < 4; ++r) {
      float s0 = accS[0][r] * SC, s1 = accS[1][r] * SC;
      float s2 = accS[2][r] * SC, s3 = accS[3][r] * SC;
      float mx = fmaxf(fmaxf(s0, s1), fmaxf(s2, s3));
      for (int o = 8; o; o >>= 1) mx = fmaxf(mx, __shfl_xor(mx, o));
      float mn = fmaxf(m[r], mx);
      float alpha = __expf(m[r] - mn);
      float p0 = __expf(s0 - mn), p1 = __expf(s1 - mn);
      float p2 = __expf(s2 - mn), p3 = __expf(s3 - mn);
      float rs = p0 + p1 + p2 + p3;
      for (int o = 8; o; o >>= 1) rs += __shfl_xor(rs, o);
      m[r] = mn;
      l[r] = l[r] * alpha + rs;
      accO[0][r] *= alpha; accO[1][r] *= alpha; accO[2][r] *= alpha;
      int prow = wv * 16 + quad * 4 + r;
      Ps[prow][l16]      = bfr(p0);
      Ps[prow][16 + l16] = bfr(p1);
      Ps[prow][32 + l16] = bfr(p2);
      Ps[prow][48 + l16] = bfr(p3);
    }
    bf16x8 pf0 = *(const bf16x8*)&Ps[wv * 16 + l16][quad * 8];
    bf16x8 pf1 = *(const bf16x8*)&Ps[wv * 16 + l16][32 + quad * 8];
#pragma unroll
    for (int ct = 0; ct < 3; ++ct) {
      bf16x8 v0 = *(const bf16x8*)&Vs[ct * 16 + l16][quad * 8];
      bf16x8 v1 = *(const bf16x8*)&Vs[ct * 16 + l16][32 + quad * 8];
      accO[ct] = __builtin_amdgcn_mfma_f32_16x16x32_bf16(pf0, v0, accO[ct], 0, 0, 0);
      accO[ct] = __builtin_amdgcn_mfma_f32_16x16x32_bf16(pf1, v1, accO[ct], 0, 0, 0);
    }
    __syncthreads();
  }
  long base = (((long)s * 2 + b) * 4 + h) * 1024;
#pragma unroll
  for (int r = 0; r < 4; ++r) {
    int row = q0 + wv * 16 + quad * 4 + r;
#pragma unroll
    for (int ct = 0; ct < 3; ++ct)
      opart[(base + row) * 48 + ct * 16 + l16] = bfr(accO[ct][r]);
    if (l16 == 0) {
      ml[(base + row) * 2]     = m[r];
      ml[(base + row) * 2 + 1] = l[r];
    }
  }
}

// ---------------- EMA / upsample / out ----------------
__global__ void k_ema(float* __restrict__ x) {
  int i = blockIdx.x * blockDim.x + threadIdx.x;
  if (i < 196608) x[196608 + i] = 0.8f * x[196608 + i] + 0.2f * x[i];
}

__global__ void k_upsample(const float* __restrict__ in, float* __restrict__ out) {
  int i = blockIdx.x * blockDim.x + threadIdx.x;
  if (i >= 2 * 2 * 64 * 64) return;
  int p = i & 4095;
  int bc = i >> 12;
  int oy = p >> 6, ox = p & 63;
  float sx = ox * (31.0f / 63.0f), sy = oy * (31.0f / 63.0f);
  int x0 = (int)sx, y0 = (int)sy;
  int x1 = min(x0 + 1, 31), y1 = min(y0 + 1, 31);
  float wx = sx - x0, wy = sy - y0;
  const float* ic = in + (long)bc * 1024;
  out[i] = ic[y0 * 32 + x0] * (1 - wx) * (1 - wy) + ic[y0 * 32 + x1] * wx * (1 - wy)
         + ic[y1 * 32 + x0] * (1 - wx) * wy      + ic[y1 * 32 + x1] * wx * wy;
}

__global__ void k_out(const float* __restrict__ cur2, void* __restrict__ out,
                      const int* __restrict__ fl) {
  int isb = *fl;
  int i = blockIdx.x * blockDim.x + threadIdx.x;
  if (i < 16384) {
    if (isb) ((bf16*)out)[i] = f2bf(cur2[i]);
    else ((float*)out)[i] = cur2[i];
  }
}

extern "C" void kernel_launch(void* const* d_in, const int* in_sizes, int n_in,
                              void* d_out, int out_size, void* d_ws, size_t ws_size,
                              hipStream_t stream) {
  const void* feats_l1 = d_in[0];
  const void* feats_l2 = d_in[1];
  const void* tok_w = d_in[3];
  const void* tok_b = d_in[4];
  const void* lcm_ln1_w = d_in[5];
  const void* lcm_ln1_b = d_in[6];
  const void* lcm_in_w  = d_in[7];
  const void* lcm_in_b  = d_in[8];
  const void* lcm_out_w = d_in[9];
  const void* lcm_out_b = d_in[10];
  const void* lcm_ln2_w = d_in[11];
  const void* lcm_ln2_b = d_in[12];
  const void* lcm_mlp_w1 = d_in[13];
  const void* lcm_mlp_b1 = d_in[14];
  const void* lcm_mlp_w2 = d_in[15];
  const void* lcm_mlp_b2 = d_in[16];
  const void* gtr_ln1_w = d_in[17];
  const void* gtr_ln1_b = d_in[18];
  const void* gtr_in_w  = d_in[19];
  const void* gtr_in_b  = d_in[20];
  const void* gtr_out_w = d_in[21];
  const void* gtr_out_b = d_in[22];
  const void* gtr_ln2_w = d_in[23];
  const void* gtr_ln2_b = d_in[24];
  const void* gtr_mlp_w1 = d_in[25];
  const void* gtr_mlp_b1 = d_in[26];
  const void* gtr_mlp_w2 = d_in[27];
  const void* gtr_mlp_b2 = d_in[28];
  const void* head_w1 = d_in[29];
  const void* head_b1 = d_in[30];
  const void* head_w2 = d_in[31];
  const void* head_b2 = d_in[32];
  const void* ref1_w1 = d_in[33];
  const void* ref1_b1 = d_in[34];
  const void* ref1_w2 = d_in[35];
  const void* ref1_b2 = d_in[36];
  const void* ref0_w1 = d_in[37];
  const void* ref0_b1 = d_in[38];
  const void* ref0_w2 = d_in[39];
  const void* ref0_b2 = d_in[40];
  (void)ws_size; (void)n_in; (void)in_sizes; (void)out_size;

  // ---- workspace layout (f-eq units; ~16.8 MB) ----
  int* flag = (int*)d_ws;
  int* oneflag = (int*)d_ws + 2;
  float* wsf = (float*)d_ws;
  float* F2   = wsf + 16;             // 393216 (unused this round; layout stability)
  float* rA   = F2 + 393216;          // 786432 : opart bf16 | A0packed
  float* rX   = rA + 786432;          // 393216 : residual x | A1packed
  float* rT   = rX + 393216;          // 393216 : tb / head-hidden | mid0packed
  float* rY   = rT + 393216;          // 393216 : mlbuf | mid1packed
  float* big  = rY + 393216;          // 1572864: qkv/vt/hid [0,851968) | Fp2+Fp1 tail
  float* fv   = big + 1572864;        // 4096 (unused)
  float* cur  = fv + 4096;            // 4096
  float* cur2 = cur + 4096;           // 16384
  float* cb1a = cur2 + 16384;         // 128
  float* cb1b = cb1a + 128;           // 16
  float* cb0a = cb1b + 16;            // 64
  float* cb0b = cb0a + 64;            // 16
  bf16* wtok  = (bf16*)(cb0b + 16);   // 12288 shorts
  float* wpk  = cb0b + 16 + 6144;
  bf16* w1p1 = (bf16*)wpk;            // 331776 shorts
  bf16* w1p2 = (bf16*)(wpk + 165888); // 18432 shorts
  bf16* w0p1 = (bf16*)(wpk + 175104); // 92160 shorts
  bf16* w0p2 = (bf16*)(wpk + 221184); // 9216 shorts

  float* x = rX;
  bf16* tb     = (bf16*)rT;
  bf16* corrTb = (bf16*)big;
  bf16* qkvbb  = (bf16*)big;
  bf16* vtb    = (bf16*)(big + 655360);
  bf16* hidb   = (bf16*)big;
  unsigned short* opart = (unsigned short*)rA;  // [4][2][4][1024][48] bf16
  float* mlbuf = rY;                            // [4][2][4][1024][2] fp32
  float* headh = rT;
  bf16* A0p   = (bf16*)rA;
  bf16* A1p   = (bf16*)rX;
  bf16* mid0p = (bf16*)rT;
  bf16* mid1p = (bf16*)rY;
  bf16* Fp2   = (bf16*)(big + 851968);   // [3][1024][128] = 393216 shorts
  bf16* Fp1   = (bf16*)(big + 1048576);  // [3][4096][64]  = 786432 shorts

  k_detect<<<1, 256, 0, stream>>>((const unsigned short*)feats_l1, flag);
  k_setone<<<1, 1, 0, stream>>>(oneflag);
  k_cvt<<<1, 256, 0, stream>>>(ref1_b1, cb1a, 128, flag);
  k_cvt<<<1, 256, 0, stream>>>(ref1_b2, cb1b, 2, flag);
  k_cvt<<<1, 256, 0, stream>>>(ref0_b1, cb0a, 64, flag);
  k_cvt<<<1, 256, 0, stream>>>(ref0_b2, cb0b, 2, flag);
  k_padtokw<<<48, 256, 0, stream>>>(tok_w, wtok, flag);
  k_packw<<<1296, 256, 0, stream>>>(ref1_w1, w1p1, 128, 128, 258, 128, 288, 331776, flag);
  k_packw<<<72, 256, 0, stream>>>(ref1_w2, w1p2, 2, 128, 128, 16, 128, 18432, flag);
  k_packw<<<360, 256, 0, stream>>>(ref0_w1, w0p1, 64, 64, 130, 64, 160, 92160, flag);
  k_packw<<<36, 256, 0, stream>>>(ref0_w2, w0p2, 2, 64, 64, 16, 64, 9216, flag);
  // pixel-major frames up front (big tail survives qkv/hid which use [0,851968))
  k_trans_feats<<<192, 256, 0, stream>>>(feats_l2, Fp2, 3, 128, 1024, flag);
  k_trans_feats<<<384, 256, 0, stream>>>(feats_l1, Fp1, 3, 64, 4096, flag);

  // ---- tokens: corr (from Fp2) then tokenizer GEMM + fused LN1(LCM0) ----
  k_corr<<<dim3(1024, 2), 64, 0, stream>>>(Fp2, corrTb);
  k_gemm_ln<0, false, 1><<<32, 256, 0, stream>>>(
      corrTb, wtok, 0, tok_b, 192, nullptr, x, tb,
      lcm_ln1_w, 0, lcm_ln1_b, 0, 2048, 64, oneflag, flag, nullptr, nullptr);

  for (int i = 0; i < 8; ++i) {
    bool lcm = i < 6;
    long j = lcm ? i : i - 6;
    const void* inw = lcm ? lcm_in_w : gtr_in_w;   long o3 = j * 110592;
    const void* inb = lcm ? lcm_in_b : gtr_in_b;   long o4 = j * 576;
    const void* ow  = lcm ? lcm_out_w : gtr_out_w; long o5 = j * 36864;
    const void* ob  = lcm ? lcm_out_b : gtr_out_b; long o6 = j * 192;
    const void* l2w = lcm ? lcm_ln2_w : gtr_ln2_w; long o7 = j * 192;
    const void* l2b = lcm ? lcm_ln2_b : gtr_ln2_b; long o8 = j * 192;
    const void* w1  = lcm ? lcm_mlp_w1 : gtr_mlp_w1; long o9 = j * 147456;
    const void* b1  = lcm ? lcm_mlp_b1 : gtr_mlp_b1; long o10 = j * 768;
    const void* w2  = lcm ? lcm_mlp_w2 : gtr_mlp_w2; long o11 = j * 147456;
    const void* b2  = lcm ? lcm_mlp_b2 : gtr_mlp_b2; long o12 = j * 192;
    bool fuse = (i != 5 && i != 7);
    const void* nlw = nullptr; const void* nlb = nullptr; long no = 0;
    if (i < 5) { nlw = lcm_ln1_w; nlb = lcm_ln1_b; no = (long)(i + 1) * 192; }
    else if (i == 6) { nlw = gtr_ln1_w; nlb = gtr_ln1_b; no = 192; }

    k_gemm_mfma<0, false, 1, 1, 1><<<dim3(9, 32), 256, 0, stream>>>(
        tb, inw, o3, inb, o4, flag, nullptr, qkvbb, 2048, 576, 192, flag, vtb);
    k_attn_mfma<<<dim3(64, 4, 2), 256, 0, stream>>>(qkvbb, vtb, opart, mlbuf);
    k_gemm_ln<0, true, 2><<<32, 256, 0, stream>>>(
        nullptr, ow, o5, ob, o6, x, x, tb, l2w, o7, l2b, o8,
        2048, 192, flag, flag, opart, mlbuf);
    k_gemm_mfma<1, false, 1, 1, 0><<<dim3(12, 32), 256, 0, stream>>>(
        tb, w1, o9, b1, o10, flag, nullptr, hidb, 2048, 768, 192, flag, nullptr);
    if (fuse) {
      k_gemm_ln<0, true, 1><<<32, 256, 0, stream>>>(
          hidb, w2, o11, b2, o12, x, x, tb, nlw, no, nlb, no,
          2048, 768, flag, flag, nullptr, nullptr);
    } else {
      k_gemm_mfma<0, true, 1, 0, 0><<<dim3(3, 32), 256, 0, stream>>>(
          hidb, w2, o11, b2, o12, flag, x, x, 2048, 192, 768, flag, nullptr);
    }
    if (i == 5) {
      k_ema<<<768, 256, 0, stream>>>(x);
      k_ln<<<512, 256, 0, stream>>>(x, tb, gtr_ln1_w, 0, gtr_ln1_b, 0, flag);
    }
  }

  // ---- head -> coarse flow ----
  k_gemm_mfma<1, false, 0, 0, 0><<<dim3(3, 32), 256, 0, stream>>>(
      x, head_w1, 0, head_b1, 0, flag, nullptr, headh, 2048, 192, 192, flag, nullptr);
  k_gemm<0, false, 1><<<dim3(1, 16), 256, 0, stream>>>(headh, head_w2, 0, head_b2, 0, nullptr,
                                                       cur, 2048, 2, 192, 192, flag);

  // ---- decoder prep: one merged zero of rA..rY, then feats fills ----
  k_zerosh<<<1920, 256, 0, stream>>>((unsigned short*)rA, 491520);
  k_fill_feats<<<128, 256, 0, stream>>>(Fp2, A1p, 128, 288, 32, 32);

  // ---- decoder level 1 (32x32): ICP=288, OC=128 ----
  for (int it = 0; it < 4; ++it) {
    k_warp_pack<<<128, 256, 0, stream>>>(Fp2, cur, A1p, 128, 288, 32, 32);
    k_conv_mfma<2, 2, 0><<<dim3(2, 32, 2), 256, 0, stream>>>(
        A1p, 288, w1p1, cb1a, nullptr, mid1p, 128, 32, 32, 5);
    k_conv_mfma<4, 1, 1><<<dim3(1, 16, 2), 256, 0, stream>>>(
        mid1p, 128, w1p2, cb1b, cur, cur, 2, 32, 32, 5);
  }
  k_upsample<<<64, 256, 0, stream>>>(cur, cur2);
  k_fill_feats<<<256, 256, 0, stream>>>(Fp1, A0p, 64, 160, 64, 64);

  // ---- decoder level 0 (64x64): ICP=160, OC=64 ----
  for (int it = 0; it < 4; ++it) {
    k_warp_pack<<<256, 256, 0, stream>>>(Fp1, cur2, A0p, 64, 160, 64, 64);
    k_conv_mfma<2, 2, 0><<<dim3(1, 128, 2), 256, 0, stream>>>(
        A0p, 160, w0p1, cb0a, nullptr, mid0p, 64, 64, 64, 6);
    k_conv_mfma<4, 1, 1><<<dim3(1, 64, 2), 256, 0, stream>>>(
        mid0p, 64, w0p2, cb0b, cur2, cur2, 2, 64, 64, 6);
  }

  k_out<<<64, 256, 0, stream>>>(cur2, d_out, flag);
}

// Round 12
// 1115.211 us; speedup vs baseline: 1.2117x; 1.2117x over previous
//
#include <hip/hip_runtime.h>
#include <hip/hip_bf16.h>

typedef __hip_bfloat16 bf16;
typedef short bf16x8 __attribute__((ext_vector_type(8)));
typedef float f32x4 __attribute__((ext_vector_type(4)));

#define DEV __device__ __forceinline__

DEV float bf2f(bf16 v) { return __bfloat162float(v); }
DEV bf16 f2bf(float v) { return __float2bfloat16(v); }
DEV unsigned short bfr(float f) {
  bf16 h = __float2bfloat16(f);
  return *reinterpret_cast<unsigned short*>(&h);
}
DEV float shf(unsigned short u) {
  unsigned int x = ((unsigned int)u) << 16;
  return *reinterpret_cast<float*>(&x);
}
DEV float gelu_exact(float x) { return 0.5f * x * (1.0f + erff(x * 0.70710678118654752f)); }

DEV float ldw(const void* p, long i, int isb) {
  return isb ? __bfloat162float(((const bf16*)p)[i]) : ((const float*)p)[i];
}

// ---------------- dtype detection + flag constants ----------------
__global__ void k_detect(const unsigned short* __restrict__ u, int* __restrict__ flag) {
  __shared__ int bad;
  if (threadIdx.x == 0) bad = 0;
  __syncthreads();
  for (int i = threadIdx.x; i < 8192; i += 256) {
    int expo = (u[i] >> 7) & 0xFF;
    if (expo >= 138) atomicOr(&bad, 1);
  }
  __syncthreads();
  if (threadIdx.x == 0) *flag = bad ? 0 : 1;
}
__global__ void k_setone(int* p) { *p = 1; }

// ---------------- convert (bf16|fp32) -> fp32 ----------------
__global__ void k_cvt(const void* __restrict__ s, float* __restrict__ d, int n,
                      const int* __restrict__ fl) {
  int isb = *fl;
  int i = blockIdx.x * blockDim.x + threadIdx.x;
  if (i < n) d[i] = ldw(s, i, isb);
}

__global__ void k_zerosh(unsigned short* __restrict__ p, int n8) {
  int i = blockIdx.x * blockDim.x + threadIdx.x;
  if (i < n8) { uint4 z = {0, 0, 0, 0}; *(uint4*)(p + (long)i * 8) = z; }
}

// tokenizer weight [192][49] (at element offset 9408) -> bf16 [192][64] zero-padded
__global__ void k_padtokw(const void* __restrict__ tw, bf16* __restrict__ dst,
                          const int* __restrict__ fl) {
  int isb = *fl;
  int i = blockIdx.x * blockDim.x + threadIdx.x;
  if (i >= 12288) return;
  int n = i >> 6, k = i & 63;
  float v = (k < 49) ? ldw(tw, 9408 + (long)n * 49 + k, isb) : 0.0f;
  dst[i] = f2bf(v);
}

// conv weight pack: dst[s][np][icp] bf16 from src [OC][ICT][9], channel remap feats|warp|flow|0
__global__ void k_packw(const void* __restrict__ src, bf16* __restrict__ dst,
                        int OC, int C, int ICT, int NP, int ICP, int n,
                        const int* __restrict__ fl) {
  int isb = *fl;
  int i = blockIdx.x * blockDim.x + threadIdx.x;
  if (i >= n) return;
  int s = i / (NP * ICP);
  int r = i - s * NP * ICP;
  int oc = r / ICP, icp = r - oc * ICP;
  float v = 0.0f;
  if (oc < OC) {
    int ic = -1;
    if (icp < C) ic = icp;
    else if (icp < 2 * C) ic = icp - C + C + 2;
    else if (icp < 2 * C + 2) ic = icp - 2 * C + C;
    if (ic >= 0 && ic < ICT) v = ldw(src, ((long)oc * ICT + ic) * 9 + s, isb);
  }
  dst[i] = f2bf(v);
}

// feats [F][C][HW] -> pixel-major bf16 [F][HW][C]; one thread per 8-channel group
__global__ void k_trans_feats(const void* __restrict__ in, bf16* __restrict__ Fp,
                              int F, int C, int HW, const int* __restrict__ fl) {
  int isb = *fl;
  int cpg = C >> 3;
  int n = F * HW * cpg;
  int i = blockIdx.x * blockDim.x + threadIdx.x;
  if (i >= n) return;
  int p = i % HW;
  int rem = i / HW;
  int c8 = rem % cpg;
  int f = rem / cpg;
  long base = (long)f * C * HW + (long)(c8 * 8) * HW + p;
  union { unsigned short u[8]; uint4 v; } pk;
#pragma unroll
  for (int j = 0; j < 8; ++j) pk.u[j] = bfr(ldw(in, base + (long)j * HW, isb));
  *(uint4*)((unsigned short*)Fp + ((long)f * HW + p) * C + c8 * 8) = pk.v;
}

// per-(pixel, c8) copy of feats frame b into padded A interior
__global__ void k_fill_feats(const bf16* __restrict__ Fp, bf16* __restrict__ Ap,
                             int C, int ICP, int H, int W) {
  int HW = H * W;
  int cpg = C >> 3;
  int n = 2 * HW * cpg;
  int i = blockIdx.x * blockDim.x + threadIdx.x;
  if (i >= n) return;
  int g = i % cpg;
  int rem = i / cpg;
  int p = rem % HW;
  int b = rem / HW;
  int h = p / W, w = p - h * W;
  const unsigned short* src = (const unsigned short*)Fp + ((long)b * HW + p) * C + g * 8;
  unsigned short* dst = (unsigned short*)Ap +
      ((long)b * (H + 2) * (W + 2) + (long)(h + 1) * (W + 2) + w + 1) * ICP + g * 8;
  *(uint4*)dst = *(const uint4*)src;
}

// per-(pixel, c8): warped frame channels [C,2C); g==0 also writes flow [2C,2C+2)
__global__ void k_warp_pack(const bf16* __restrict__ Fp, const float* __restrict__ flow,
                            bf16* __restrict__ Ap, int C, int ICP, int H, int W) {
  int HW = H * W;
  int cpg = C >> 3;
  int n = 2 * HW * cpg;
  int i = blockIdx.x * blockDim.x + threadIdx.x;
  if (i >= n) return;
  int g = i % cpg;
  int rem = i / cpg;
  int p = rem % HW;
  int b = rem / HW;
  int h = p / W, w = p - h * W;
  const float* fl = flow + (long)b * 2 * HW;
  float fx = fl[p], fy = fl[HW + p];
  unsigned short* drow = (unsigned short*)Ap +
      ((long)b * (H + 2) * (W + 2) + (long)(h + 1) * (W + 2) + w + 1) * ICP;
  if (g == 0) { drow[2 * C] = bfr(fx); drow[2 * C + 1] = bfr(fy); }
  float x = fminf(fmaxf((float)w + fx, 0.0f), (float)(W - 1));
  float y = fminf(fmaxf((float)h + fy, 0.0f), (float)(H - 1));
  int x0 = (int)floorf(x), y0 = (int)floorf(y);
  int x1 = min(x0 + 1, W - 1), y1 = min(y0 + 1, H - 1);
  float wx = x - (float)x0, wy = y - (float)y0;
  float w00 = (1 - wx) * (1 - wy), w01 = wx * (1 - wy);
  float w10 = (1 - wx) * wy, w11 = wx * wy;
  const unsigned short* f = (const unsigned short*)Fp + (long)(b + 1) * HW * C;
  int c = g * 8;
  union { unsigned short u[8]; uint4 v; } a = { .v = *(const uint4*)(f + (long)(y0 * W + x0) * C + c) };
  union { unsigned short u[8]; uint4 v; } bb = { .v = *(const uint4*)(f + (long)(y0 * W + x1) * C + c) };
  union { unsigned short u[8]; uint4 v; } cc = { .v = *(const uint4*)(f + (long)(y1 * W + x0) * C + c) };
  union { unsigned short u[8]; uint4 v; } dd = { .v = *(const uint4*)(f + (long)(y1 * W + x1) * C + c) };
  union { unsigned short u[8]; uint4 v; } o;
#pragma unroll
  for (int j = 0; j < 8; ++j) {
    float v = shf(a.u[j]) * w00 + shf(bb.u[j]) * w01 + shf(cc.u[j]) * w10 + shf(dd.u[j]) * w11;
    o.u[j] = bfr(v);
  }
  *(uint4*)(drow + C + c) = o.v;
}

// ---------------- MFMA implicit-GEMM 3x3 conv, barrier-light schedule -----------------
template <int MW, int NT, int MODE>
__global__ __launch_bounds__(256) void k_conv_mfma(
    const bf16* __restrict__ Ap, int ICP, const bf16* __restrict__ Wp,
    const float* __restrict__ bias, const float* __restrict__ res,
    void* __restrict__ out, int NOUT, int H, int W, int lgW) {
  constexpr int NWN = 4 / MW;
  constexpr int BM = MW * 16;
  constexpr int BN = NWN * NT * 16;
  __shared__ unsigned short Asm[198][40];
  __shared__ unsigned short Wsm[9 * BN][40];
  int tid = threadIdx.x;
  int wv = tid >> 6, ln = tid & 63, quad = ln >> 4, l16 = ln & 15;
  int wm = wv % MW, wn = wv / MW;
  int n0 = blockIdx.x * BN;
  int m0 = blockIdx.y * BM;
  int b = blockIdx.z;
  int Wp2 = W + 2;
  int CW = (BM < W) ? BM : W;
  int lgCW = (CW == 64) ? 6 : 5;
  int RO = (BM > W) ? (BM >> lgW) : 1;
  int ACW = CW + 2;
  int AR = (RO + 2) * ACW;
  int py0 = m0 >> lgW;
  int px0 = m0 & (W - 1);
  const unsigned short* A = (const unsigned short*)Ap + (long)b * (H + 2) * Wp2 * ICP;
  int NPr = (MODE == 0) ? NOUT : 16;
  int nk = ICP >> 5;
  f32x4 acc[NT] = {};
  int mm_local = wm * 16 + l16;
  int plr = mm_local >> lgCW;
  int plc = mm_local & (CW - 1);
  for (int kc = 0; kc < nk; ++kc) {
    for (int i = tid; i < AR * 4; i += 256) {
      int r = i >> 2, c4 = i & 3;
      int sr = r / ACW, sc = r - sr * ACW;
      long g = ((long)(py0 + sr) * Wp2 + px0 + sc) * ICP + kc * 32 + c4 * 8;
      *(uint4*)&Asm[r][c4 * 8] = *(const uint4*)(A + g);
    }
    for (int i = tid; i < 9 * BN * 4; i += 256) {
      int r = i >> 2, c4 = i & 3;
      int s = r / BN, nl = r - s * BN;
      long g = ((long)s * NPr + n0 + nl) * ICP + kc * 32 + c4 * 8;
      *(uint4*)&Wsm[r][c4 * 8] = *(const uint4*)((const unsigned short*)Wp + g);
    }
    __syncthreads();
#pragma unroll
    for (int s = 0; s < 9; ++s) {
      int ky = s / 3, kx = s - ky * 3;
      bf16x8 af = *(const bf16x8*)&Asm[(plr + ky) * ACW + plc + kx][quad * 8];
#pragma unroll
      for (int nt = 0; nt < NT; ++nt) {
        bf16x8 wf = *(const bf16x8*)&Wsm[s * BN + (wn * NT + nt) * 16 + l16][quad * 8];
        acc[nt] = __builtin_amdgcn_mfma_f32_16x16x32_bf16(af, wf, acc[nt], 0, 0, 0);
      }
    }
    __syncthreads();
  }
  if (MODE == 0) {
#pragma unroll
    for (int nt = 0; nt < NT; ++nt) {
      int n = n0 + (wn * NT + nt) * 16 + l16;
      float bv = bias[n];
#pragma unroll
      for (int r = 0; r < 4; ++r) {
        int mmo = m0 + wm * 16 + quad * 4 + r;
        int py = mmo >> lgW, px = mmo & (W - 1);
        float v = gelu_exact(acc[nt][r] + bv);
        ((unsigned short*)out)[((long)b * (H + 2) * Wp2 + (long)(py + 1) * Wp2 + px + 1) * NOUT + n]
            = bfr(v);
      }
    }
  } else {
    int n = l16;
    if (wn == 0 && n < 2) {
      float bv = bias[n];
      int HW = H * W;
#pragma unroll
      for (int r = 0; r < 4; ++r) {
        int mmo = m0 + wm * 16 + quad * 4 + r;
        float v = acc[0][r] + bv + res[(long)b * 2 * HW + (long)n * HW + mmo];
        ((float*)out)[(long)b * 2 * HW + (long)n * HW + mmo] = v;
      }
    }
  }
}

// ---------------- local correlation from pixel-major bf16 Fp2, bf16 out, stride 64 -------
__global__ void k_corr(const bf16* __restrict__ Fp2, bf16* __restrict__ corrT) {
  __shared__ unsigned short f1r[128];
  int p = blockIdx.x;
  int b = blockIdx.y;
  int t = threadIdx.x;  // 64
  const unsigned short* f1 = (const unsigned short*)Fp2 + ((long)b * 1024 + p) * 128;
  if (t < 16) *(uint4*)&f1r[t * 8] = *(const uint4*)(f1 + t * 8);
  __syncthreads();
  long rowo = ((long)b * 1024 + p) * 64;
  if (t < 49) {
    int dy = t / 7 - 3, dx = t % 7 - 3;
    int h = p >> 5, w = p & 31;
    int p2 = (((h - dy) & 31) << 5) | ((w - dx) & 31);
    const unsigned short* f2 = (const unsigned short*)Fp2 + ((long)(b + 1) * 1024 + p2) * 128;
    float s = 0.0f;
    for (int c = 0; c < 128; c += 8) {
      union { unsigned short u[8]; uint4 v; } av = { .v = *(const uint4*)&f1r[c] };
      union { unsigned short u[8]; uint4 v; } bv = { .v = *(const uint4*)(f2 + c) };
#pragma unroll
      for (int j = 0; j < 8; ++j) s += shf(av.u[j]) * shf(bv.u[j]);
    }
    corrT[rowo + t] = f2bf(s * 0.08838834764831845f);
  } else {
    corrT[rowo + t] = f2bf(0.0f);
  }
}

// ---------------- LayerNorm (D=192), 4 rows/block, bf16 out ----------------
__global__ __launch_bounds__(256) void k_ln(const float* __restrict__ src, bf16* __restrict__ dst,
                     const void* __restrict__ w, long woff,
                     const void* __restrict__ b, long boff,
                     const int* __restrict__ fl) {
  int isb = *fl;
  int row = blockIdx.x * 4 + (threadIdx.x >> 6);
  int t = threadIdx.x & 63;
  const float* s = src + (long)row * 192;
  float e0 = s[t], e1 = s[t + 64], e2 = s[t + 128];
  float sum = e0 + e1 + e2;
  for (int o = 32; o; o >>= 1) sum += __shfl_xor(sum, o);
  float mean = sum * (1.0f / 192.0f);
  float d0 = e0 - mean, d1 = e1 - mean, d2 = e2 - mean;
  float vs = d0 * d0 + d1 * d1 + d2 * d2;
  for (int o = 32; o; o >>= 1) vs += __shfl_xor(vs, o);
  float rstd = rsqrtf(vs * (1.0f / 192.0f) + 1e-5f);
  bf16* o_ = dst + (long)row * 192;
  o_[t]       = f2bf(d0 * rstd * ldw(w, woff + t, isb)       + ldw(b, boff + t, isb));
  o_[t + 64]  = f2bf(d1 * rstd * ldw(w, woff + t + 64, isb)  + ldw(b, boff + t + 64, isb));
  o_[t + 128] = f2bf(d2 * rstd * ldw(w, woff + t + 128, isb) + ldw(b, boff + t + 128, isb));
}

// ---------------- MFMA bf16 GEMM ----------------
// AMODE: 0 = fp32 A, 1 = bf16 A, 2 = A from 4-way split-K attention partials (fused merge).
// VT: also scatter V-region (n>=384) into vt[b][h][48][1024].
template <int ACT, bool HASRES, int AMODE, int OUTBF, int VT>
__global__ __launch_bounds__(256) void k_gemm_mfma(
    const void* __restrict__ A, const void* __restrict__ W, long woff,
    const void* __restrict__ bias, long boff, const int* __restrict__ flb,
    const float* __restrict__ res, void* __restrict__ C,
    int M, int N, int K, const int* __restrict__ fl,
    const unsigned short* __restrict__ mop, const float* __restrict__ mml,
    bf16* __restrict__ vtout) {
  int isb = *fl;
  __shared__ unsigned short Asm[64][40];
  __shared__ unsigned short Wsm[64][40];
  int tid = threadIdx.x;
  int wv = tid >> 6, ln = tid & 63;
  int quad = ln >> 4, l16 = ln & 15;
  int m0 = blockIdx.y * 64, n0 = blockIdx.x * 64;
  int srow = tid >> 2;
  int skc = (tid & 3) * 8;
  f32x4 acc[4] = {};
  for (int k0 = 0; k0 < K; k0 += 32) {
    if (AMODE == 1) {
      const unsigned short* ap = (const unsigned short*)A + (long)(m0 + srow) * K + k0 + skc;
      *(uint4*)&Asm[srow][skc] = *(const uint4*)ap;
    } else if (AMODE == 0) {
      const float* ap = (const float*)A + (long)(m0 + srow) * K + k0 + skc;
      float4 a0 = *(const float4*)ap;
      float4 a1 = *(const float4*)(ap + 4);
      union { unsigned short u[8]; uint4 v; } pk;
      pk.u[0] = bfr(a0.x); pk.u[1] = bfr(a0.y); pk.u[2] = bfr(a0.z); pk.u[3] = bfr(a0.w);
      pk.u[4] = bfr(a1.x); pk.u[5] = bfr(a1.y); pk.u[6] = bfr(a1.z); pk.u[7] = bfr(a1.w);
      *(uint4*)&Asm[srow][skc] = pk.v;
    } else {
      // fused attention merge: y[m][k] from 4 split partials (bf16 O, fp32 m/l)
      int m = m0 + srow;
      int row = m & 1023, bb = m >> 10;
      int ks = k0 + skc;
      int h = ks / 48;       // whole 8-run shares one head (48 % 8 == 0)
      int d0 = ks - h * 48;
      long idx[4];
      float ms[4], ls[4];
      float Ms = -1e30f;
#pragma unroll
      for (int s = 0; s < 4; ++s) {
        idx[s] = (((long)s * 2 + bb) * 4 + h) * 1024 + row;
        ms[s] = mml[idx[s] * 2];
        ls[s] = mml[idx[s] * 2 + 1];
        Ms = fmaxf(Ms, ms[s]);
      }
      float e[4], L = 0.0f;
#pragma unroll
      for (int s = 0; s < 4; ++s) { e[s] = __expf(ms[s] - Ms); L += ls[s] * e[s]; }
      float invL = 1.0f / L;
      union { unsigned short u[8]; uint4 v; } pk;
#pragma unroll
      for (int j = 0; j < 8; ++j) {
        float o = 0.0f;
#pragma unroll
        for (int s = 0; s < 4; ++s) o += shf(mop[idx[s] * 48 + d0 + j]) * e[s];
        pk.u[j] = bfr(o * invL);
      }
      *(uint4*)&Asm[srow][skc] = pk.v;
    }
    {
      long eo = woff + (long)(n0 + srow) * K + k0 + skc;
      if (isb) {
        *(uint4*)&Wsm[srow][skc] = *(const uint4*)((const unsigned short*)W + eo);
      } else {
        const float* wp = (const float*)W + eo;
        float4 w0 = *(const float4*)wp;
        float4 w1 = *(const float4*)(wp + 4);
        union { unsigned short u[8]; uint4 v; } pk;
        pk.u[0] = bfr(w0.x); pk.u[1] = bfr(w0.y); pk.u[2] = bfr(w0.z); pk.u[3] = bfr(w0.w);
        pk.u[4] = bfr(w1.x); pk.u[5] = bfr(w1.y); pk.u[6] = bfr(w1.z); pk.u[7] = bfr(w1.w);
        *(uint4*)&Wsm[srow][skc] = pk.v;
      }
    }
    __syncthreads();
    bf16x8 af = *(const bf16x8*)&Asm[wv * 16 + l16][quad * 8];
#pragma unroll
    for (int nt = 0; nt < 4; ++nt) {
      bf16x8 wf = *(const bf16x8*)&Wsm[nt * 16 + l16][quad * 8];
      acc[nt] = __builtin_amdgcn_mfma_f32_16x16x32_bf16(af, wf, acc[nt], 0, 0, 0);
    }
    __syncthreads();
  }
  int isbb = *flb;
#pragma unroll
  for (int nt = 0; nt < 4; ++nt) {
    int n = n0 + nt * 16 + l16;
    float bv = ldw(bias, boff + n, isbb);
#pragma unroll
    for (int r = 0; r < 4; ++r) {
      int m = m0 + wv * 16 + quad * 4 + r;
      float v = acc[nt][r] + bv;
      if (HASRES) v += res[(long)m * N + n];
      if (ACT == 1) v = gelu_exact(v);
      if (OUTBF) ((bf16*)C)[(long)m * N + n] = f2bf(v);
      else ((float*)C)[(long)m * N + n] = v;
      if (VT) {
        if (n >= 384) {
          int hh = (n - 384) / 48, dd = (n - 384) % 48;
          int row = m & 1023, bb = m >> 10;
          vtout[((long)(bb * 4 + hh) * 48 + dd) * 1024 + row] = f2bf(v);
        }
      }
    }
  }
}

// ---------------- fp32 GEMM (head output; FLOW=1 writes [b][2][1024] layout) -------------
template <int ACT, bool HASRES, int FLOW>
__global__ __launch_bounds__(256) void k_gemm(const float* __restrict__ A,
                                              const void* __restrict__ W, long woff,
                                              const void* __restrict__ bias, long boff,
                                              const float* __restrict__ res,
                                              float* __restrict__ C, int M, int N, int K, int Kw,
                                              const int* __restrict__ fl) {
  int isb = *fl;
  __shared__ float As[16][132];
  __shared__ float Ws[16][68];
  int tid = threadIdx.x;
  int tx = tid & 15, ty = tid >> 4;
  int m0 = blockIdx.y * 128, n0 = blockIdx.x * 64;
  float acc[8][4] = {};
  for (int k0 = 0; k0 < K; k0 += 16) {
#pragma unroll
    for (int i = 0; i < 2; ++i) {
      int idx4 = tid + i * 256;
      int mm = idx4 >> 2, kc = (idx4 & 3) * 4;
      float4 v = *(const float4*)(A + (long)(m0 + mm) * K + k0 + kc);
      As[kc][mm] = v.x; As[kc + 1][mm] = v.y; As[kc + 2][mm] = v.z; As[kc + 3][mm] = v.w;
    }
#pragma unroll
    for (int i = 0; i < 4; ++i) {
      int idx = tid + i * 256;
      int nn = idx >> 4, kk = idx & 15;
      int gn = n0 + nn, gk = k0 + kk;
      Ws[kk][nn] = (gn < N && gk < Kw) ? ldw(W, woff + (long)gn * Kw + gk, isb) : 0.0f;
    }
    __syncthreads();
#pragma unroll
    for (int kk = 0; kk < 16; ++kk) {
      float4 a0 = *(const float4*)&As[kk][ty * 8];
      float4 a1 = *(const float4*)&As[kk][ty * 8 + 4];
      float4 w4 = *(const float4*)&Ws[kk][tx * 4];
      float av[8] = {a0.x, a0.y, a0.z, a0.w, a1.x, a1.y, a1.z, a1.w};
      float wv[4] = {w4.x, w4.y, w4.z, w4.w};
#pragma unroll
      for (int i = 0; i < 8; ++i)
#pragma unroll
        for (int j = 0; j < 4; ++j) acc[i][j] += av[i] * wv[j];
    }
    __syncthreads();
  }
#pragma unroll
  for (int i = 0; i < 8; ++i) {
    int gm = m0 + ty * 8 + i;
#pragma unroll
    for (int j = 0; j < 4; ++j) {
      int gn = n0 + tx * 4 + j;
      if (gn >= N) continue;
      float v = acc[i][j] + ldw(bias, boff + gn, isb);
      if (HASRES) v += res[(long)gm * N + gn];
      if (ACT == 1) v = gelu_exact(v);
      if (FLOW) {
        int bb2 = gm >> 10, p = gm & 1023;
        C[((long)bb2 * 2 + gn) * 1024 + p] = v;
      } else {
        C[(long)gm * N + gn] = v;
      }
    }
  }
}

// ---------------- MFMA flash attention, split-K (4 splits of 4 chunks) -------------------
__global__ __launch_bounds__(256) void k_attn_mfma(const bf16* __restrict__ qkv,
                                                   const bf16* __restrict__ vt,
                                                   unsigned short* __restrict__ opart,
                                                   float* __restrict__ ml) {
  __shared__ unsigned short Qs[64][72];
  __shared__ unsigned short Ks[64][72];
  __shared__ unsigned short Vs[48][72];
  __shared__ unsigned short Ps[64][72];
  int tid = threadIdx.x;
  int wv = tid >> 6, ln = tid & 63, quad = ln >> 4, l16 = ln & 15;
  int h = blockIdx.y, b = blockIdx.z;
  int qt = blockIdx.x >> 2, s = blockIdx.x & 3;
  int q0 = qt * 64;
  const unsigned short* qp = (const unsigned short*)qkv + (long)b * 1024 * 576;
  const unsigned short* vp = (const unsigned short*)vt + ((long)(b * 4 + h) * 48) * 1024;
  for (int i = tid; i < 384; i += 256) {
    int r = i / 6, c = i % 6;
    *(uint4*)&Qs[r][c * 8] = *(const uint4*)(qp + (long)(q0 + r) * 576 + h * 48 + c * 8);
  }
  for (int i = tid; i < 128; i += 256) {
    int r = i >> 1, c = 6 + (i & 1);
    uint4 z = {0, 0, 0, 0};
    *(uint4*)&Qs[r][c * 8] = z;
  }
  float m[4] = {-1e30f, -1e30f, -1e30f, -1e30f};
  float l[4] = {0.0f, 0.0f, 0.0f, 0.0f};
  f32x4 accO[3] = {};
  const float SC = 0.14433756729740643f;
  for (int kc = s * 4; kc < s * 4 + 4; ++kc) {
    int k0 = kc * 64;
    for (int i = tid; i < 384; i += 256) {
      int r = i / 6, c = i % 6;
      *(uint4*)&Ks[r][c * 8] = *(const uint4*)(qp + (long)(k0 + r) * 576 + 192 + h * 48 + c * 8);
    }
    for (int i = tid; i < 128; i += 256) {
      int r = i >> 1, c = 6 + (i & 1);
      uint4 z = {0, 0, 0, 0};
      *(uint4*)&Ks[r][c * 8] = z;
    }
    for (int i = tid; i < 384; i += 256) {
      int d = i >> 3, c = i & 7;
      *(uint4*)&Vs[d][c * 8] = *(const uint4*)(vp + (long)d * 1024 + k0 + c * 8);
    }
    __syncthreads();
    f32x4 accS[4] = {};
    bf16x8 a0 = *(const bf16x8*)&Qs[wv * 16 + l16][quad * 8];
    bf16x8 a1 = *(const bf16x8*)&Qs[wv * 16 + l16][32 + quad * 8];
#pragma unroll
    for (int ct = 0; ct < 4; ++ct) {
      bf16x8 b0 = *(const bf16x8*)&Ks[ct * 16 + l16][quad * 8];
      bf16x8 b1 = *(const bf16x8*)&Ks[ct * 16 + l16][32 + quad * 8];
      accS[ct] = __builtin_amdgcn_mfma_f32_16x16x32_bf16(a0, b0, accS[ct], 0, 0, 0);
      accS[ct] = __builtin_amdgcn_mfma_f32_16x16x32_bf16(a1, b1, accS[ct], 0, 0, 0);
    }
#pragma unroll
    for (int r = 0; r < 4; ++r) {
      float s0 = accS[0][r] * SC, s1 = accS[1][r] * SC;
      float s2 = accS[2][r] * SC, s3 = accS[3][r] * SC;
      float mx = fmaxf(fmaxf(s0, s1), fmaxf(s2, s3));
      for (int o = 8; o; o >>= 1) mx = fmaxf(mx, __shfl_xor(mx, o));
      float mn = fmaxf(m[r], mx);
      float alpha = __expf(m[r] - mn);
      float p0 = __expf(s0 - mn), p1 = __expf(s1 - mn);
      float p2 = __expf(s2 - mn), p3 = __expf(s3 - mn);
      float rs = p0 + p1 + p2 + p3;
      for (int o = 8; o; o >>= 1) rs += __shfl_xor(rs, o);
      m[r] = mn;
      l[r] = l[r] * alpha + rs;
      accO[0][r] *= alpha; accO[1][r] *= alpha; accO[2][r] *= alpha;
      int prow = wv * 16 + quad * 4 + r;
      Ps[prow][l16]      = bfr(p0);
      Ps[prow][16 + l16] = bfr(p1);
      Ps[prow][32 + l16] = bfr(p2);
      Ps[prow][48 + l16] = bfr(p3);
    }
    bf16x8 pf0 = *(const bf16x8*)&Ps[wv * 16 + l16][quad * 8];
    bf16x8 pf1 = *(const bf16x8*)&Ps[wv * 16 + l16][32 + quad * 8];
#pragma unroll
    for (int ct = 0; ct < 3; ++ct) {
      bf16x8 v0 = *(const bf16x8*)&Vs[ct * 16 + l16][quad * 8];
      bf16x8 v1 = *(const bf16x8*)&Vs[ct * 16 + l16][32 + quad * 8];
      accO[ct] = __builtin_amdgcn_mfma_f32_16x16x32_bf16(pf0, v0, accO[ct], 0, 0, 0);
      accO[ct] = __builtin_amdgcn_mfma_f32_16x16x32_bf16(pf1, v1, accO[ct], 0, 0, 0);
    }
    __syncthreads();
  }
  long base = (((long)s * 2 + b) * 4 + h) * 1024;
#pragma unroll
  for (int r = 0; r < 4; ++r) {
    int row = q0 + wv * 16 + quad * 4 + r;
#pragma unroll
    for (int ct = 0; ct < 3; ++ct)
      opart[(base + row) * 48 + ct * 16 + l16] = bfr(accO[ct][r]);
    if (l16 == 0) {
      ml[(base + row) * 2]     = m[r];
      ml[(base + row) * 2 + 1] = l[r];
    }
  }
}

// ---------------- EMA / upsample / out ----------------
__global__ void k_ema(float* __restrict__ x) {
  int i = blockIdx.x * blockDim.x + threadIdx.x;
  if (i < 196608) x[196608 + i] = 0.8f * x[196608 + i] + 0.2f * x[i];
}

__global__ void k_upsample(const float* __restrict__ in, float* __restrict__ out) {
  int i = blockIdx.x * blockDim.x + threadIdx.x;
  if (i >= 2 * 2 * 64 * 64) return;
  int p = i & 4095;
  int bc = i >> 12;
  int oy = p >> 6, ox = p & 63;
  float sx = ox * (31.0f / 63.0f), sy = oy * (31.0f / 63.0f);
  int x0 = (int)sx, y0 = (int)sy;
  int x1 = min(x0 + 1, 31), y1 = min(y0 + 1, 31);
  float wx = sx - x0, wy = sy - y0;
  const float* ic = in + (long)bc * 1024;
  out[i] = ic[y0 * 32 + x0] * (1 - wx) * (1 - wy) + ic[y0 * 32 + x1] * wx * (1 - wy)
         + ic[y1 * 32 + x0] * (1 - wx) * wy      + ic[y1 * 32 + x1] * wx * wy;
}

__global__ void k_out(const float* __restrict__ cur2, void* __restrict__ out,
                      const int* __restrict__ fl) {
  int isb = *fl;
  int i = blockIdx.x * blockDim.x + threadIdx.x;
  if (i < 16384) {
    if (isb) ((bf16*)out)[i] = f2bf(cur2[i]);
    else ((float*)out)[i] = cur2[i];
  }
}

extern "C" void kernel_launch(void* const* d_in, const int* in_sizes, int n_in,
                              void* d_out, int out_size, void* d_ws, size_t ws_size,
                              hipStream_t stream) {
  const void* feats_l1 = d_in[0];
  const void* feats_l2 = d_in[1];
  const void* tok_w = d_in[3];
  const void* tok_b = d_in[4];
  const void* lcm_ln1_w = d_in[5];
  const void* lcm_ln1_b = d_in[6];
  const void* lcm_in_w  = d_in[7];
  const void* lcm_in_b  = d_in[8];
  const void* lcm_out_w = d_in[9];
  const void* lcm_out_b = d_in[10];
  const void* lcm_ln2_w = d_in[11];
  const void* lcm_ln2_b = d_in[12];
  const void* lcm_mlp_w1 = d_in[13];
  const void* lcm_mlp_b1 = d_in[14];
  const void* lcm_mlp_w2 = d_in[15];
  const void* lcm_mlp_b2 = d_in[16];
  const void* gtr_ln1_w = d_in[17];
  const void* gtr_ln1_b = d_in[18];
  const void* gtr_in_w  = d_in[19];
  const void* gtr_in_b  = d_in[20];
  const void* gtr_out_w = d_in[21];
  const void* gtr_out_b = d_in[22];
  const void* gtr_ln2_w = d_in[23];
  const void* gtr_ln2_b = d_in[24];
  const void* gtr_mlp_w1 = d_in[25];
  const void* gtr_mlp_b1 = d_in[26];
  const void* gtr_mlp_w2 = d_in[27];
  const void* gtr_mlp_b2 = d_in[28];
  const void* head_w1 = d_in[29];
  const void* head_b1 = d_in[30];
  const void* head_w2 = d_in[31];
  const void* head_b2 = d_in[32];
  const void* ref1_w1 = d_in[33];
  const void* ref1_b1 = d_in[34];
  const void* ref1_w2 = d_in[35];
  const void* ref1_b2 = d_in[36];
  const void* ref0_w1 = d_in[37];
  const void* ref0_b1 = d_in[38];
  const void* ref0_w2 = d_in[39];
  const void* ref0_b2 = d_in[40];
  (void)ws_size; (void)n_in; (void)in_sizes; (void)out_size;

  // ---- workspace layout (f-eq units; ~16.8 MB) ----
  int* flag = (int*)d_ws;
  int* oneflag = (int*)d_ws + 2;
  float* wsf = (float*)d_ws;
  float* F2   = wsf + 16;             // 393216 (spare; layout stability)
  float* rA   = F2 + 393216;          // 786432 : opart bf16 | A0packed
  float* rX   = rA + 786432;          // 393216 : residual x | A1packed
  float* rT   = rX + 393216;          // 393216 : tb / head-hidden | mid0packed
  float* rY   = rT + 393216;          // 393216 : mlbuf | mid1packed
  float* big  = rY + 393216;          // 1572864: qkv/vt/hid [0,851968) | Fp2+Fp1 tail
  float* fv   = big + 1572864;        // 4096 (unused)
  float* cur  = fv + 4096;            // 4096
  float* cur2 = cur + 4096;           // 16384
  float* cb1a = cur2 + 16384;         // 128
  float* cb1b = cb1a + 128;           // 16
  float* cb0a = cb1b + 16;            // 64
  float* cb0b = cb0a + 64;            // 16
  bf16* wtok  = (bf16*)(cb0b + 16);   // 12288 shorts
  float* wpk  = cb0b + 16 + 6144;
  bf16* w1p1 = (bf16*)wpk;            // 331776 shorts
  bf16* w1p2 = (bf16*)(wpk + 165888); // 18432 shorts
  bf16* w0p1 = (bf16*)(wpk + 175104); // 92160 shorts
  bf16* w0p2 = (bf16*)(wpk + 221184); // 9216 shorts

  float* x = rX;
  bf16* tb     = (bf16*)rT;
  bf16* corrTb = (bf16*)big;
  bf16* qkvbb  = (bf16*)big;
  bf16* vtb    = (bf16*)(big + 655360);
  bf16* hidb   = (bf16*)big;
  unsigned short* opart = (unsigned short*)rA;  // [4][2][4][1024][48] bf16
  float* mlbuf = rY;                            // [4][2][4][1024][2] fp32
  float* headh = rT;
  bf16* A0p   = (bf16*)rA;
  bf16* A1p   = (bf16*)rX;
  bf16* mid0p = (bf16*)rT;
  bf16* mid1p = (bf16*)rY;
  bf16* Fp2   = (bf16*)(big + 851968);   // [3][1024][128] = 393216 shorts
  bf16* Fp1   = (bf16*)(big + 1048576);  // [3][4096][64]  = 786432 shorts

  k_detect<<<1, 256, 0, stream>>>((const unsigned short*)feats_l1, flag);
  k_setone<<<1, 1, 0, stream>>>(oneflag);
  k_cvt<<<1, 256, 0, stream>>>(ref1_b1, cb1a, 128, flag);
  k_cvt<<<1, 256, 0, stream>>>(ref1_b2, cb1b, 2, flag);
  k_cvt<<<1, 256, 0, stream>>>(ref0_b1, cb0a, 64, flag);
  k_cvt<<<1, 256, 0, stream>>>(ref0_b2, cb0b, 2, flag);
  k_padtokw<<<48, 256, 0, stream>>>(tok_w, wtok, flag);
  k_packw<<<1296, 256, 0, stream>>>(ref1_w1, w1p1, 128, 128, 258, 128, 288, 331776, flag);
  k_packw<<<72, 256, 0, stream>>>(ref1_w2, w1p2, 2, 128, 128, 16, 128, 18432, flag);
  k_packw<<<360, 256, 0, stream>>>(ref0_w1, w0p1, 64, 64, 130, 64, 160, 92160, flag);
  k_packw<<<36, 256, 0, stream>>>(ref0_w2, w0p2, 2, 64, 64, 16, 64, 9216, flag);
  // pixel-major frames up front (big tail survives qkv/hid which use [0,851968))
  k_trans_feats<<<192, 256, 0, stream>>>(feats_l2, Fp2, 3, 128, 1024, flag);
  k_trans_feats<<<384, 256, 0, stream>>>(feats_l1, Fp1, 3, 64, 4096, flag);

  // ---- tokens: corr (from Fp2) then tokenizer GEMM ----
  k_corr<<<dim3(1024, 2), 64, 0, stream>>>(Fp2, corrTb);
  k_gemm_mfma<0, false, 1, 0, 0><<<dim3(3, 32), 256, 0, stream>>>(
      corrTb, wtok, 0, tok_b, 192, flag, nullptr, x, 2048, 192, 64, oneflag,
      nullptr, nullptr, nullptr);

  auto run_block = [&](const void* ln1w, long o1, const void* ln1b, long o2,
                       const void* inw, long o3, const void* inb, long o4,
                       const void* ow, long o5, const void* ob, long o6,
                       const void* ln2w, long o7, const void* ln2b, long o8,
                       const void* w1, long o9, const void* b1, long o10,
                       const void* w2, long o11, const void* b2, long o12) {
    k_ln<<<512, 256, 0, stream>>>(x, tb, ln1w, o1, ln1b, o2, flag);
    // qkv GEMM: bf16 out + fused V-transpose scatter
    k_gemm_mfma<0, false, 1, 1, 1><<<dim3(9, 32), 256, 0, stream>>>(
        tb, inw, o3, inb, o4, flag, nullptr, qkvbb, 2048, 576, 192, flag,
        nullptr, nullptr, vtb);
    k_attn_mfma<<<dim3(64, 4, 2), 256, 0, stream>>>(qkvbb, vtb, opart, mlbuf);
    // out-proj GEMM: fused 4-way split-K merge as A-operand
    k_gemm_mfma<0, true, 2, 0, 0><<<dim3(3, 32), 256, 0, stream>>>(
        nullptr, ow, o5, ob, o6, flag, x, x, 2048, 192, 192, flag,
        opart, mlbuf, nullptr);
    k_ln<<<512, 256, 0, stream>>>(x, tb, ln2w, o7, ln2b, o8, flag);
    k_gemm_mfma<1, false, 1, 1, 0><<<dim3(12, 32), 256, 0, stream>>>(
        tb, w1, o9, b1, o10, flag, nullptr, hidb, 2048, 768, 192, flag,
        nullptr, nullptr, nullptr);
    k_gemm_mfma<0, true, 1, 0, 0><<<dim3(3, 32), 256, 0, stream>>>(
        hidb, w2, o11, b2, o12, flag, x, x, 2048, 192, 768, flag,
        nullptr, nullptr, nullptr);
  };

  for (int i = 0; i < 6; ++i) {
    run_block(lcm_ln1_w, (long)i * 192, lcm_ln1_b, (long)i * 192,
              lcm_in_w, (long)i * 110592, lcm_in_b, (long)i * 576,
              lcm_out_w, (long)i * 36864, lcm_out_b, (long)i * 192,
              lcm_ln2_w, (long)i * 192, lcm_ln2_b, (long)i * 192,
              lcm_mlp_w1, (long)i * 147456, lcm_mlp_b1, (long)i * 768,
              lcm_mlp_w2, (long)i * 147456, lcm_mlp_b2, (long)i * 192);
  }
  k_ema<<<768, 256, 0, stream>>>(x);

  for (int i = 0; i < 2; ++i) {
    run_block(gtr_ln1_w, (long)i * 192, gtr_ln1_b, (long)i * 192,
              gtr_in_w, (long)i * 110592, gtr_in_b, (long)i * 576,
              gtr_out_w, (long)i * 36864, gtr_out_b, (long)i * 192,
              gtr_ln2_w, (long)i * 192, gtr_ln2_b, (long)i * 192,
              gtr_mlp_w1, (long)i * 147456, gtr_mlp_b1, (long)i * 768,
              gtr_mlp_w2, (long)i * 147456, gtr_mlp_b2, (long)i * 192);
  }

  // ---- head -> coarse flow (fused [b][2][1024] write) ----
  k_gemm_mfma<1, false, 0, 0, 0><<<dim3(3, 32), 256, 0, stream>>>(
      x, head_w1, 0, head_b1, 0, flag, nullptr, headh, 2048, 192, 192, flag,
      nullptr, nullptr, nullptr);
  k_gemm<0, false, 1><<<dim3(1, 16), 256, 0, stream>>>(headh, head_w2, 0, head_b2, 0, nullptr,
                                                       cur, 2048, 2, 192, 192, flag);

  // ---- decoder prep: one merged zero of rA..rY, then feats fills ----
  k_zerosh<<<1920, 256, 0, stream>>>((unsigned short*)rA, 491520);
  k_fill_feats<<<128, 256, 0, stream>>>(Fp2, A1p, 128, 288, 32, 32);

  // ---- decoder level 1 (32x32): ICP=288, OC=128 ----
  for (int it = 0; it < 4; ++it) {
    k_warp_pack<<<128, 256, 0, stream>>>(Fp2, cur, A1p, 128, 288, 32, 32);
    k_conv_mfma<2, 2, 0><<<dim3(2, 32, 2), 256, 0, stream>>>(
        A1p, 288, w1p1, cb1a, nullptr, mid1p, 128, 32, 32, 5);
    k_conv_mfma<4, 1, 1><<<dim3(1, 16, 2), 256, 0, stream>>>(
        mid1p, 128, w1p2, cb1b, cur, cur, 2, 32, 32, 5);
  }
  k_upsample<<<64, 256, 0, stream>>>(cur, cur2);
  k_fill_feats<<<256, 256, 0, stream>>>(Fp1, A0p, 64, 160, 64, 64);

  // ---- decoder level 0 (64x64): ICP=160, OC=64 ----
  for (int it = 0; it < 4; ++it) {
    k_warp_pack<<<256, 256, 0, stream>>>(Fp1, cur2, A0p, 64, 160, 64, 64);
    k_conv_mfma<2, 2, 0><<<dim3(1, 128, 2), 256, 0, stream>>>(
        A0p, 160, w0p1, cb0a, nullptr, mid0p, 64, 64, 64, 6);
    k_conv_mfma<4, 1, 1><<<dim3(1, 64, 2), 256, 0, stream>>>(
        mid0p, 64, w0p2, cb0b, cur2, cur2, 2, 64, 64, 6);
  }

  k_out<<<64, 256, 0, stream>>>(cur2, d_out, flag);
}